// Round 9
// baseline (291.383 us; speedup 1.0000x reference)
//
#include <hip/hip_runtime.h>

#define NODES 50000
#define EDGES 800000
#define FIN 128
#define DIM 256
#define GRAPHS 256
#define PAD_M 50048   // 782 * 64
#define SCAN_BLOCKS ((NODES + 255) / 256)       // 196
#define PRESCALE_BLOCKS (NODES * FIN / 4 / 256) // 6250 exact
#define HBLOCKS 256                             // histogram copies / edge chunks
#define CHUNK (EDGES / HBLOCKS)                 // 3125 edges per block, exact
#define HALF_N 25000                            // nodes per LDS half
#define HALF_W 12500                            // u32 words per half (2 nodes/u32)

typedef short short8 __attribute__((ext_vector_type(8)));
typedef float f32x4 __attribute__((ext_vector_type(4)));

__device__ __forceinline__ float bf2f(uint u) { return __uint_as_float(u << 16); }
__device__ __forceinline__ ushort f2bf(float f) {
    uint b = __float_as_uint(f);
    return (ushort)((b + 0x7FFF + ((b >> 16) & 1)) >> 16);
}

// Per-block LDS histogram of idx[] over its 3125-edge chunk, u16-packed
// (2 nodes per u32; per-block count <= 3125 so no overflow), node range in
// 2 halves of 25000 (50KB LDS each). Dump = streaming writes, NO global atomics.
__global__ __launch_bounds__(256) void hist_kernel(const int* __restrict__ idx,
                                                   uint* __restrict__ histG) {
    __shared__ uint cur[HALF_W];
    int b = blockIdx.x, tid = threadIdx.x;
    int base = b * CHUNK;
    for (int half = 0; half < 2; ++half) {
        for (int j = tid; j < HALF_W; j += 256) cur[j] = 0;
        __syncthreads();
        int lo = half * HALF_N;
        for (int e = base + tid; e < base + CHUNK; e += 256) {
            int local = idx[e] - lo;
            if ((unsigned)local < (unsigned)HALF_N)
                atomicAdd(&cur[local >> 1], 1u << ((local & 1) * 16));
        }
        __syncthreads();
        uint* dstp = histG + (size_t)b * (2 * HALF_W) + half * HALF_W;
        for (int j = tid; j < HALF_W; j += 256) dstp[j] = cur[j];
        __syncthreads();
    }
}

// Sum the 256 copies -> deg_in / norms; in-place transform histIn into
// per-block EXCLUSIVE prefixes (packed u16) = scatter cursor bases.
// histOut is only summed (out_norm).
__global__ __launch_bounds__(256) void reduce_hist_kernel(uint* __restrict__ histIn,
                                                          const uint* __restrict__ histOut,
                                                          int* __restrict__ deg_in,
                                                          float* __restrict__ in_norm,
                                                          float* __restrict__ out_norm) {
    int t32 = blockIdx.x * 256 + threadIdx.x;
    if (t32 >= 2 * HALF_W) return;
    uint lo = 0, hi = 0;
#pragma unroll 4
    for (int c = 0; c < HBLOCKS; ++c) {
        size_t a = (size_t)c * (2 * HALF_W) + t32;
        uint u = histIn[a];
        histIn[a] = lo | (hi << 16);       // exclusive prefix over blocks (fits u16: <= deg)
        lo += u & 0xFFFFu;
        hi += u >> 16;
    }
    uint olo = 0, ohi = 0;
#pragma unroll 4
    for (int c = 0; c < HBLOCKS; ++c) {
        uint u = histOut[(size_t)c * (2 * HALF_W) + t32];
        olo += u & 0xFFFFu;
        ohi += u >> 16;
    }
    int n0 = (t32 < HALF_W) ? 2 * t32 : HALF_N + 2 * (t32 - HALF_W);
    deg_in[n0]     = (int)lo;
    deg_in[n0 + 1] = (int)hi;
    in_norm[n0]      = rsqrtf(fmaxf((float)lo, 1.0f));
    in_norm[n0 + 1]  = rsqrtf(fmaxf((float)hi, 1.0f));
    out_norm[n0]     = rsqrtf(fmaxf((float)olo, 1.0f));
    out_norm[n0 + 1] = rsqrtf(fmaxf((float)ohi, 1.0f));
}

// Phase 1 of row_start scan: per-256-node block sums.
__global__ __launch_bounds__(256) void scan_partials(const int* __restrict__ deg_in,
                                                     int* __restrict__ block_sums, int n) {
    __shared__ int red[4];
    int i = blockIdx.x * 256 + threadIdx.x;
    int v = (i < n) ? deg_in[i] : 0;
    int wave = threadIdx.x >> 6, lane = threadIdx.x & 63;
#pragma unroll
    for (int off = 32; off > 0; off >>= 1) v += __shfl_down(v, off);
    if (lane == 0) red[wave] = v;
    __syncthreads();
    if (threadIdx.x == 0) block_sums[blockIdx.x] = red[0] + red[1] + red[2] + red[3];
}

// Phase 2: scan the block sums (nb <= 256); also zero norm_sum for this launch.
__global__ __launch_bounds__(256) void scan_blocksums(int* __restrict__ block_sums,
                                                      int* __restrict__ row_start,
                                                      float* __restrict__ norm_sum, int nb, int n) {
    __shared__ int s[256];
    int t = threadIdx.x;
    if (t == 0) *norm_sum = 0.0f;
    int v = (t < nb) ? block_sums[t] : 0;
    s[t] = v;
    __syncthreads();
#pragma unroll
    for (int off = 1; off < 256; off <<= 1) {
        int u = (t >= off) ? s[t - off] : 0;
        __syncthreads();
        s[t] += u;
        __syncthreads();
    }
    if (t < nb) block_sums[t] = s[t] - v;          // exclusive prefix
    if (t == nb - 1) row_start[n] = s[t];          // total
}

// Phase 3: intra-block exclusive scan + block offset -> row_start.
__global__ __launch_bounds__(256) void scan_final(const int* __restrict__ deg,
                                                  const int* __restrict__ block_sums,
                                                  int* __restrict__ row_start, int n) {
    __shared__ int s[256];
    int t = threadIdx.x;
    int i = blockIdx.x * 256 + t;
    int v = (i < n) ? deg[i] : 0;
    s[t] = v;
    __syncthreads();
#pragma unroll
    for (int off = 1; off < 256; off <<= 1) {
        int u = (t >= off) ? s[t - off] : 0;
        __syncthreads();
        s[t] += u;
        __syncthreads();
    }
    if (i < n) row_start[i] = block_sums[blockIdx.x] + s[t] - v;
}

// Scatter with LDS cursors seeded from the per-block exclusive prefixes.
// Each block owns disjoint, exact slot ranges per dst node -> no global atomics.
__global__ __launch_bounds__(256) void scatter_lds_kernel(const int* __restrict__ src,
                                                          const int* __restrict__ dst,
                                                          const uint* __restrict__ histIn,
                                                          const int* __restrict__ row_start,
                                                          int* __restrict__ src_sorted) {
    __shared__ uint cur[HALF_W];
    int b = blockIdx.x, tid = threadIdx.x;
    int base = b * CHUNK;
    for (int half = 0; half < 2; ++half) {
        const uint* offp = histIn + (size_t)b * (2 * HALF_W) + half * HALF_W;
        for (int j = tid; j < HALF_W; j += 256) cur[j] = offp[j];
        __syncthreads();
        int lo = half * HALF_N;
        for (int e = base + tid; e < base + CHUNK; e += 256) {
            int d = dst[e];
            int local = d - lo;
            if ((unsigned)local < (unsigned)HALF_N) {
                int sel = (local & 1) * 16;
                uint old = atomicAdd(&cur[local >> 1], 1u << sel);
                int pos = row_start[d] + (int)((old >> sel) & 0xFFFFu);
                src_sorted[pos] = src[e];
            }
        }
        __syncthreads();
    }
}

// Fused: xs = bf16(x * out_norm[row]) | W1T = bf16(W1^T) | W2T = bf16(W2^T).
__global__ __launch_bounds__(256) void prep_kernel(const float* __restrict__ x,
                                                   const float* __restrict__ out_norm,
                                                   ushort* __restrict__ xs,
                                                   const float* __restrict__ W1,
                                                   ushort* __restrict__ W1T,
                                                   const float* __restrict__ W2,
                                                   ushort* __restrict__ W2T) {
    int b = blockIdx.x;
    if (b < PRESCALE_BLOCKS) {
        int t = b * 256 + threadIdx.x;            // < NODES*FIN/4
        int row = t >> 5;                         // FIN/4 = 32 float4 per row
        float on = out_norm[row];
        float4 v = ((const float4*)x)[t];
        ushort4 o;
        o.x = f2bf(v.x * on); o.y = f2bf(v.y * on);
        o.z = f2bf(v.z * on); o.w = f2bf(v.w * on);
        ((ushort4*)xs)[t] = o;
    } else if (b < PRESCALE_BLOCKS + FIN * DIM / 256) {
        int t = (b - PRESCALE_BLOCKS) * 256 + threadIdx.x;   // < 32768
        int n = t >> 7, k = t & 127;
        W1T[t] = f2bf(W1[(size_t)k * DIM + n]);
    } else {
        int t = (b - PRESCALE_BLOCKS - FIN * DIM / 256) * 256 + threadIdx.x;  // < 65536
        int n = t >> 8, k = t & 255;
        W2T[t] = f2bf(W2[(size_t)k * DIM + n]);
    }
}

// Gather-sum aggregation, bf16 in/out, fp32 accumulate. One wave per node.
// Wave-uniform work scalarized: 8 edge indices fetched with ONE lane-indexed
// dword load, moved to SGPRs via readlane; feature loads are then
// [SGPR row base + lane voffset] with zero per-lane address VALU. Unpack is
// 2 ops/dword (lo: u<<16; hi: u & 0xFFFF0000 is already the bf16's f32 value).
template<int D>
__global__ __launch_bounds__(256) void agg_kernel(const ushort* __restrict__ in,
                                                  const int* __restrict__ row_start,
                                                  const int* __restrict__ src_sorted,
                                                  const float* __restrict__ in_norm,
                                                  ushort* __restrict__ out) {
    constexpr int VPL = D / 64;       // bf16 per lane (2 or 4)
    constexpr int NU = VPL / 2;       // dwords per lane (1 or 2)
    int wave = threadIdx.x >> 6, lane = threadIdx.x & 63;
    int node = blockIdx.x * 4 + wave;
    if (node >= NODES) return;
    int e0 = row_start[node], e1 = row_start[node + 1];
    float acc[VPL] = {};
    int e = e0;
    int nfull = (e1 - e0) >> 3;
    for (int it = 0; it < nfull; ++it, e += 8) {
        int iv = src_sorted[e + (lane & 7)];   // one load covers all 8 indices
        uint u[8][NU];
#pragma unroll
        for (int j = 0; j < 8; ++j) {
            int sj = __builtin_amdgcn_readlane(iv, j);            // SGPR index
            const uint* prow = (const uint*)(in + (size_t)sj * D); // uniform base
            if constexpr (NU == 2) {
                uint2 uv = ((const uint2*)prow)[lane];
                u[j][0] = uv.x; u[j][1] = uv.y;
            } else {
                u[j][0] = prow[lane];
            }
        }
#pragma unroll
        for (int j = 0; j < 8; ++j)
#pragma unroll
            for (int q = 0; q < NU; ++q) {
                acc[2*q]   += __uint_as_float(u[j][q] << 16);
                acc[2*q+1] += __uint_as_float(u[j][q] & 0xFFFF0000u);
            }
    }
    for (; e < e1; ++e) {                       // tail: <= 7 edges
        int sj = __builtin_amdgcn_readfirstlane(src_sorted[e]);
        const uint* prow = (const uint*)(in + (size_t)sj * D);
#pragma unroll
        for (int q = 0; q < NU; ++q) {
            uint uu = prow[lane * NU + q];
            acc[2*q]   += __uint_as_float(uu << 16);
            acc[2*q+1] += __uint_as_float(uu & 0xFFFF0000u);
        }
    }
    float inn = in_norm[node];
    uint* po = (uint*)(out + (size_t)node * D) + lane * NU;
#pragma unroll
    for (int q = 0; q < NU; ++q) {
        uint lo = f2bf(acc[2*q] * inn);
        uint hi = f2bf(acc[2*q+1] * inn);
        po[q] = lo | (hi << 16);
    }
}

// MFMA GEMM: C[M,256] = A[M,K](bf16) @ W + bias. WT[256][K] bf16, no LDS staging.
// MODE 0: out bf16 = relu(acc+bias)*scale[row]     (h1s, pre-scaled for next gather)
// MODE 1: out bf16 = acc+bias, fused row-L2-norm accumulation into norm_sum
template<int K, int MODE>
__global__ __launch_bounds__(256) void gemm_mfma_kernel(const ushort* __restrict__ A,
                                                        const ushort* __restrict__ WT,
                                                        const float* __restrict__ bias,
                                                        ushort* __restrict__ Cout,
                                                        const float* __restrict__ scale,
                                                        float* __restrict__ norm_sum,
                                                        int M) {
    __shared__ float rowsq[4][64];
    int lane = threadIdx.x & 63, wave = threadIdx.x >> 6;
    int m0 = blockIdx.x * 64, n0 = wave * 64;
    int ll = lane & 15, lh = lane >> 4;
    f32x4 acc[4][4] = {};
    const ushort* Ab = A  + (size_t)(m0 + ll) * K + lh * 8;
    const ushort* Bb = WT + (size_t)(n0 + ll) * K + lh * 8;
#pragma unroll
    for (int k0 = 0; k0 < K; k0 += 32) {
        short8 a[4], b[4];
#pragma unroll
        for (int mi = 0; mi < 4; ++mi) a[mi] = *(const short8*)(Ab + (size_t)mi * 16 * K + k0);
#pragma unroll
        for (int ni = 0; ni < 4; ++ni) b[ni] = *(const short8*)(Bb + (size_t)ni * 16 * K + k0);
#pragma unroll
        for (int mi = 0; mi < 4; ++mi)
#pragma unroll
            for (int ni = 0; ni < 4; ++ni)
                acc[mi][ni] = __builtin_amdgcn_mfma_f32_16x16x32_bf16(a[mi], b[ni], acc[mi][ni], 0, 0, 0);
    }
#pragma unroll
    for (int mi = 0; mi < 4; ++mi) {
#pragma unroll
        for (int r = 0; r < 4; ++r) {
            int row = m0 + mi * 16 + lh * 4 + r;
            float sc = (MODE == 0 && row < M) ? scale[row] : 1.0f;
            float p = 0.0f;
#pragma unroll
            for (int ni = 0; ni < 4; ++ni) {
                int col = n0 + ni * 16 + ll;
                float v = acc[mi][ni][r] + bias[col];
                if (MODE == 0) v = fmaxf(v, 0.0f) * sc;
                else p += v * v;
                if (row < M) Cout[(size_t)row * DIM + col] = f2bf(v);
            }
            if (MODE == 1) {
#pragma unroll
                for (int m = 1; m < 16; m <<= 1) p += __shfl_xor(p, m);
                if (ll == 0) rowsq[wave][mi * 16 + lh * 4 + r] = p;
            }
        }
    }
    if (MODE == 1) {
        __syncthreads();
        if (threadIdx.x < 64) {
            int lr = threadIdx.x;
            float s = rowsq[0][lr] + rowsq[1][lr] + rowsq[2][lr] + rowsq[3][lr];
            float l = (m0 + lr < M) ? sqrtf(s) : 0.0f;
#pragma unroll
            for (int m = 32; m > 0; m >>= 1) l += __shfl_down(l, m);
            if (lr == 0) atomicAdd(norm_sum, l);
        }
    }
}

// One block per graph (n2g is sorted): binary-search node range, no atomics,
// factor computed inline. Writes every output element exactly once.
__global__ __launch_bounds__(256) void pool_kernel(const ushort* __restrict__ h2,
                                                   const int* __restrict__ n2g,
                                                   const float* __restrict__ norm_sum,
                                                   float* __restrict__ out) {
    int g = blockIdx.x, f = threadIdx.x;
    int lo = 0, hi = NODES;
    while (lo < hi) { int mid = (lo + hi) >> 1; if (n2g[mid] < g) lo = mid + 1; else hi = mid; }
    int start = lo;
    hi = NODES;
    while (lo < hi) { int mid = (lo + hi) >> 1; if (n2g[mid] < g + 1) lo = mid + 1; else hi = mid; }
    int end = lo;
    float acc = 0.0f;
    int i = start;
    for (; i + 3 < end; i += 4) {
        acc += (bf2f((uint)h2[(size_t)(i + 0) * DIM + f]) + bf2f((uint)h2[(size_t)(i + 1) * DIM + f]))
             + (bf2f((uint)h2[(size_t)(i + 2) * DIM + f]) + bf2f((uint)h2[(size_t)(i + 3) * DIM + f]));
    }
    for (; i < end; ++i) acc += bf2f((uint)h2[(size_t)i * DIM + f]);
    float factor = 16.0f * (float)NODES / *norm_sum;   // sqrt(256) / mean row norm
    out[(size_t)g * DIM + f] = acc * factor;
}

extern "C" void kernel_launch(void* const* d_in, const int* in_sizes, int n_in,
                              void* d_out, int out_size, void* d_ws, size_t ws_size,
                              hipStream_t stream) {
    const float* x  = (const float*)d_in[0];
    const float* W1 = (const float*)d_in[1];
    const float* b1 = (const float*)d_in[2];
    const float* W2 = (const float*)d_in[3];
    const float* b2 = (const float*)d_in[4];
    const int* src = (const int*)d_in[5];
    const int* dst = (const int*)d_in[6];
    const int* n2g = (const int*)d_in[7];
    float* out = (float*)d_out;

    char* ws = (char*)d_ws;
    size_t off = 0;
    auto alloc = [&](size_t bytes) {
        char* p = ws + off;
        off = (off + bytes + 255) & ~(size_t)255;
        return p;
    };
    uint* histIn    = (uint*)alloc((size_t)HBLOCKS * 2 * HALF_W * 4);  // 25.6 MB
    uint* histOut   = (uint*)alloc((size_t)HBLOCKS * 2 * HALF_W * 4);  // 25.6 MB
    int* deg_in     = (int*)alloc(NODES * 4);
    float* out_norm = (float*)alloc(NODES * 4);
    float* in_norm  = (float*)alloc(NODES * 4);
    int* row_start  = (int*)alloc((NODES + 1) * 4);
    int* src_sorted = (int*)alloc(EDGES * 4);
    int* block_sums = (int*)alloc(SCAN_BLOCKS * 4);
    float* norm_sum = (float*)alloc(4);
    ushort* W1T     = (ushort*)alloc((size_t)DIM * FIN * 2);   // [256][128]
    ushort* W2T     = (ushort*)alloc((size_t)DIM * DIM * 2);   // [256][256]
    // Aliased feature regions:
    // P0: xs [PAD_M][128] bf16 -> low half of A2 | P1: A1 [PAD_M][128] -> high half of A2
    // H : h1s [PAD_M][256] bf16 -> reused as h2 (agg2 consumed h1s before gemm2 writes)
    ushort* xs  = (ushort*)alloc((size_t)PAD_M * FIN * 2);
    ushort* A1  = (ushort*)alloc((size_t)PAD_M * FIN * 2);
    ushort* h1s = (ushort*)alloc((size_t)PAD_M * DIM * 2);
    ushort* A2 = xs;          // [PAD_M][256] bf16, overlays P0+P1
    ushort* h2 = h1s;         // [PAD_M][256] bf16, overlays H

    // CSR build: LDS histograms, zero global atomics anywhere in the pipeline.
    hist_kernel<<<HBLOCKS, 256, 0, stream>>>(dst, histIn);
    hist_kernel<<<HBLOCKS, 256, 0, stream>>>(src, histOut);
    reduce_hist_kernel<<<(2 * HALF_W + 255) / 256, 256, 0, stream>>>(histIn, histOut,
                                                                     deg_in, in_norm, out_norm);
    scan_partials<<<SCAN_BLOCKS, 256, 0, stream>>>(deg_in, block_sums, NODES);
    scan_blocksums<<<1, 256, 0, stream>>>(block_sums, row_start, norm_sum, SCAN_BLOCKS, NODES);
    scan_final<<<SCAN_BLOCKS, 256, 0, stream>>>(deg_in, block_sums, row_start, NODES);
    scatter_lds_kernel<<<HBLOCKS, 256, 0, stream>>>(src, dst, histIn, row_start, src_sorted);

    prep_kernel<<<PRESCALE_BLOCKS + FIN * DIM / 256 + DIM * DIM / 256, 256, 0, stream>>>(
        x, out_norm, xs, W1, W1T, W2, W2T);

    // Layer 1
    agg_kernel<FIN><<<(NODES + 3) / 4, 256, 0, stream>>>(xs, row_start, src_sorted, in_norm, A1);
    gemm_mfma_kernel<FIN, 0><<<PAD_M / 64, 256, 0, stream>>>(A1, W1T, b1, h1s, out_norm, norm_sum, NODES);

    // Layer 2 (gemm2 fuses row-norm accumulation, writes bf16 h2)
    agg_kernel<DIM><<<(NODES + 3) / 4, 256, 0, stream>>>(h1s, row_start, src_sorted, in_norm, A2);
    gemm_mfma_kernel<DIM, 1><<<PAD_M / 64, 256, 0, stream>>>(A2, W2T, b2, h2, nullptr, norm_sum, NODES);

    // Per-graph sum-pool with inline factor; covers all graphs, no memset needed.
    pool_kernel<<<GRAPHS, 256, 0, stream>>>(h2, n2g, norm_sum, out);
}

// Round 10
// 268.970 us; speedup vs baseline: 1.0833x; 1.0833x over previous
//
#include <hip/hip_runtime.h>

#define NODES 50000
#define EDGES 800000
#define FIN 128
#define DIM 256
#define GRAPHS 256
#define PAD_M 50048   // 782 * 64
#define PRESCALE_BLOCKS (NODES * FIN / 4 / 256) // 6250 exact
#define HBLOCKS 256                             // histogram copies / edge chunks
#define CHUNK (EDGES / HBLOCKS)                 // 3125 edges per block, exact
#define HALF_N 25000                            // nodes per LDS half
#define HALF_W 12500                            // u32 words per half (2 nodes/u32)
#define RB 98                                   // reduce/scan blocks (512 nodes each)

typedef short short8 __attribute__((ext_vector_type(8)));
typedef float f32x4 __attribute__((ext_vector_type(4)));

__device__ __forceinline__ float bf2f(uint u) { return __uint_as_float(u << 16); }
__device__ __forceinline__ ushort f2bf(float f) {
    uint b = __float_as_uint(f);
    return (ushort)((b + 0x7FFF + ((b >> 16) & 1)) >> 16);
}

// Both histograms in ONE dispatch: blocks [0,256) dst->histIn, [256,512) src->histOut.
// Per-block LDS histogram over its 3125-edge chunk, u16-packed (2 nodes/u32,
// count <= 3125), node range in 2 halves of 25000. Streaming dump, no global atomics.
__global__ __launch_bounds__(256) void hist2_kernel(const int* __restrict__ src,
                                                    const int* __restrict__ dst,
                                                    uint* __restrict__ histIn,
                                                    uint* __restrict__ histOut) {
    __shared__ uint cur[HALF_W];
    int b = blockIdx.x & 255, tid = threadIdx.x;
    const int* idx = (blockIdx.x < HBLOCKS) ? dst : src;
    uint* histG    = (blockIdx.x < HBLOCKS) ? histIn : histOut;
    int base = b * CHUNK;
    for (int half = 0; half < 2; ++half) {
        for (int j = tid; j < HALF_W; j += 256) cur[j] = 0;
        __syncthreads();
        int lo = half * HALF_N;
        for (int e = base + tid; e < base + CHUNK; e += 256) {
            int local = idx[e] - lo;
            if ((unsigned)local < (unsigned)HALF_N)
                atomicAdd(&cur[local >> 1], 1u << ((local & 1) * 16));
        }
        __syncthreads();
        uint* dstp = histG + (size_t)b * (2 * HALF_W) + half * HALF_W;
        for (int j = tid; j < HALF_W; j += 256) dstp[j] = cur[j];
        __syncthreads();
    }
}

// Sum the 256 copies -> deg_in / norms; in-place transform histIn into per-block
// EXCLUSIVE prefixes (packed u16); ALSO emit per-512-node block sums (fused
// scan phase 1: word t32 covers nodes 2*t32, 2*t32+1, so block b covers the
// contiguous node range [512b, 512b+512)).
__global__ __launch_bounds__(256) void reduce_hist_kernel(uint* __restrict__ histIn,
                                                          const uint* __restrict__ histOut,
                                                          int* __restrict__ deg_in,
                                                          float* __restrict__ in_norm,
                                                          float* __restrict__ out_norm,
                                                          int* __restrict__ block_sums) {
    __shared__ int red[4];
    int t32 = blockIdx.x * 256 + threadIdx.x;
    uint lo = 0, hi = 0;
    if (t32 < 2 * HALF_W) {
#pragma unroll 4
        for (int c = 0; c < HBLOCKS; ++c) {
            size_t a = (size_t)c * (2 * HALF_W) + t32;
            uint u = histIn[a];
            histIn[a] = lo | (hi << 16);       // exclusive prefix over blocks
            lo += u & 0xFFFFu;
            hi += u >> 16;
        }
        uint olo = 0, ohi = 0;
#pragma unroll 4
        for (int c = 0; c < HBLOCKS; ++c) {
            uint u = histOut[(size_t)c * (2 * HALF_W) + t32];
            olo += u & 0xFFFFu;
            ohi += u >> 16;
        }
        int n0 = 2 * t32;
        deg_in[n0]     = (int)lo;
        deg_in[n0 + 1] = (int)hi;
        in_norm[n0]      = rsqrtf(fmaxf((float)lo, 1.0f));
        in_norm[n0 + 1]  = rsqrtf(fmaxf((float)hi, 1.0f));
        out_norm[n0]     = rsqrtf(fmaxf((float)olo, 1.0f));
        out_norm[n0 + 1] = rsqrtf(fmaxf((float)ohi, 1.0f));
    }
    // fused scan phase 1: block sum of deg over nodes [512b, 512b+512)
    int s = (int)(lo + hi);
    int wave = threadIdx.x >> 6, lane = threadIdx.x & 63;
#pragma unroll
    for (int off = 32; off > 0; off >>= 1) s += __shfl_down(s, off);
    if (lane == 0) red[wave] = s;
    __syncthreads();
    if (threadIdx.x == 0) block_sums[blockIdx.x] = red[0] + red[1] + red[2] + red[3];
}

// Scan the RB block sums; zero norm_sum; write row_start[n] = total.
__global__ __launch_bounds__(256) void scan_blocksums(int* __restrict__ block_sums,
                                                      int* __restrict__ row_start,
                                                      float* __restrict__ norm_sum, int nb, int n) {
    __shared__ int s[256];
    int t = threadIdx.x;
    if (t == 0) *norm_sum = 0.0f;
    int v = (t < nb) ? block_sums[t] : 0;
    s[t] = v;
    __syncthreads();
#pragma unroll
    for (int off = 1; off < 256; off <<= 1) {
        int u = (t >= off) ? s[t - off] : 0;
        __syncthreads();
        s[t] += u;
        __syncthreads();
    }
    if (t < nb) block_sums[t] = s[t] - v;          // exclusive prefix
    if (t == nb - 1) row_start[n] = s[t];          // total
}

// Fused: [scan_final over 512-node blocks | prescale-cast xs | cast W1T | cast W2T].
// The prep parts depend only on reduce_hist (out_norm), satisfied by dispatch order.
__global__ __launch_bounds__(256) void scanfinal_prep_kernel(const int* __restrict__ deg,
                                                             const int* __restrict__ block_sums,
                                                             int* __restrict__ row_start,
                                                             const float* __restrict__ x,
                                                             const float* __restrict__ out_norm,
                                                             ushort* __restrict__ xs,
                                                             const float* __restrict__ W1,
                                                             ushort* __restrict__ W1T,
                                                             const float* __restrict__ W2,
                                                             ushort* __restrict__ W2T) {
    __shared__ int s[256];
    int b = blockIdx.x, t = threadIdx.x;
    if (b < RB) {
        // exclusive scan of 512 degrees (2 per thread) + block offset
        int i0 = b * 512 + 2 * t;
        int v0 = (i0 < NODES) ? deg[i0] : 0;
        int v1 = (i0 + 1 < NODES) ? deg[i0 + 1] : 0;
        int pair = v0 + v1;
        s[t] = pair;
        __syncthreads();
#pragma unroll
        for (int off = 1; off < 256; off <<= 1) {
            int u = (t >= off) ? s[t - off] : 0;
            __syncthreads();
            s[t] += u;
            __syncthreads();
        }
        int excl = block_sums[b] + s[t] - pair;
        if (i0 < NODES) row_start[i0] = excl;
        if (i0 + 1 < NODES) row_start[i0 + 1] = excl + v0;
    } else if (b < RB + PRESCALE_BLOCKS) {
        int i = (b - RB) * 256 + t;               // < NODES*FIN/4
        int row = i >> 5;                         // FIN/4 = 32 float4 per row
        float on = out_norm[row];
        float4 v = ((const float4*)x)[i];
        ushort4 o;
        o.x = f2bf(v.x * on); o.y = f2bf(v.y * on);
        o.z = f2bf(v.z * on); o.w = f2bf(v.w * on);
        ((ushort4*)xs)[i] = o;
    } else if (b < RB + PRESCALE_BLOCKS + FIN * DIM / 256) {
        int i = (b - RB - PRESCALE_BLOCKS) * 256 + t;   // < 32768
        int n = i >> 7, k = i & 127;
        W1T[i] = f2bf(W1[(size_t)k * DIM + n]);
    } else {
        int i = (b - RB - PRESCALE_BLOCKS - FIN * DIM / 256) * 256 + t;  // < 65536
        int n = i >> 8, k = i & 255;
        W2T[i] = f2bf(W2[(size_t)k * DIM + n]);
    }
}

// Scatter with LDS cursors seeded from the per-block exclusive prefixes.
// Each block owns disjoint, exact slot ranges per dst node -> no global atomics.
__global__ __launch_bounds__(256) void scatter_lds_kernel(const int* __restrict__ src,
                                                          const int* __restrict__ dst,
                                                          const uint* __restrict__ histIn,
                                                          const int* __restrict__ row_start,
                                                          int* __restrict__ src_sorted) {
    __shared__ uint cur[HALF_W];
    int b = blockIdx.x, tid = threadIdx.x;
    int base = b * CHUNK;
    for (int half = 0; half < 2; ++half) {
        const uint* offp = histIn + (size_t)b * (2 * HALF_W) + half * HALF_W;
        for (int j = tid; j < HALF_W; j += 256) cur[j] = offp[j];
        __syncthreads();
        int lo = half * HALF_N;
        for (int e = base + tid; e < base + CHUNK; e += 256) {
            int d = dst[e];
            int local = d - lo;
            if ((unsigned)local < (unsigned)HALF_N) {
                int sel = (local & 1) * 16;
                uint old = atomicAdd(&cur[local >> 1], 1u << sel);
                int pos = row_start[d] + (int)((old >> sel) & 0xFFFFu);
                src_sorted[pos] = src[e];
            }
        }
        __syncthreads();
    }
}

// Gather-sum aggregation, bf16 in/out, fp32 accumulate. One wave per node.
// 8-edge unroll, branchless masked tail (round-8 form: measured at the
// gather-stream roofline ~7.2 TB/s logical; do not touch).
template<int D>
__global__ __launch_bounds__(256) void agg_kernel(const ushort* __restrict__ in,
                                                  const int* __restrict__ row_start,
                                                  const int* __restrict__ src_sorted,
                                                  const float* __restrict__ in_norm,
                                                  ushort* __restrict__ out) {
    constexpr int VPL = D / 64;       // bf16 per lane (2 or 4)
    constexpr int NU = VPL / 2;       // uint loads per lane
    int wave = threadIdx.x >> 6, lane = threadIdx.x & 63;
    int node = blockIdx.x * 4 + wave;
    if (node >= NODES) return;
    int off = lane * VPL;
    int e0 = row_start[node], e1 = row_start[node + 1];
    float acc[VPL] = {};
    int niter = (e1 - e0 + 7) >> 3;
    for (int it = 0; it < niter; ++it) {
        int eb = e0 + it * 8;
        int idx[8];
#pragma unroll
        for (int j = 0; j < 8; ++j) idx[j] = src_sorted[min(eb + j, e1 - 1)];
        uint u[8][NU];
#pragma unroll
        for (int j = 0; j < 8; ++j) {
            const uint* p = (const uint*)(in + (size_t)idx[j] * D + off);
#pragma unroll
            for (int q = 0; q < NU; ++q) u[j][q] = p[q];
        }
#pragma unroll
        for (int j = 0; j < 8; ++j) {
            uint ok = (eb + j < e1) ? 0xFFFFFFFFu : 0u;
#pragma unroll
            for (int q = 0; q < NU; ++q) {
                uint uu = u[j][q] & ok;
                acc[2*q]   += bf2f(uu & 0xFFFFu);
                acc[2*q+1] += bf2f(uu >> 16);
            }
        }
    }
    float inn = in_norm[node];
    uint* po = (uint*)(out + (size_t)node * D + off);
#pragma unroll
    for (int q = 0; q < NU; ++q) {
        uint lo = f2bf(acc[2*q] * inn);
        uint hi = f2bf(acc[2*q+1] * inn);
        po[q] = lo | (hi << 16);
    }
}

// MFMA GEMM: C[M,256] = A[M,K](bf16) @ W + bias. WT[256][K] bf16, no LDS staging.
// MODE 0: out bf16 = relu(acc+bias)*scale[row]     (h1s, pre-scaled for next gather)
// MODE 1: out bf16 = acc+bias, fused row-L2-norm accumulation into norm_sum
template<int K, int MODE>
__global__ __launch_bounds__(256) void gemm_mfma_kernel(const ushort* __restrict__ A,
                                                        const ushort* __restrict__ WT,
                                                        const float* __restrict__ bias,
                                                        ushort* __restrict__ Cout,
                                                        const float* __restrict__ scale,
                                                        float* __restrict__ norm_sum,
                                                        int M) {
    __shared__ float rowsq[4][64];
    int lane = threadIdx.x & 63, wave = threadIdx.x >> 6;
    int m0 = blockIdx.x * 64, n0 = wave * 64;
    int ll = lane & 15, lh = lane >> 4;
    f32x4 acc[4][4] = {};
    const ushort* Ab = A  + (size_t)(m0 + ll) * K + lh * 8;
    const ushort* Bb = WT + (size_t)(n0 + ll) * K + lh * 8;
#pragma unroll
    for (int k0 = 0; k0 < K; k0 += 32) {
        short8 a[4], b[4];
#pragma unroll
        for (int mi = 0; mi < 4; ++mi) a[mi] = *(const short8*)(Ab + (size_t)mi * 16 * K + k0);
#pragma unroll
        for (int ni = 0; ni < 4; ++ni) b[ni] = *(const short8*)(Bb + (size_t)ni * 16 * K + k0);
#pragma unroll
        for (int mi = 0; mi < 4; ++mi)
#pragma unroll
            for (int ni = 0; ni < 4; ++ni)
                acc[mi][ni] = __builtin_amdgcn_mfma_f32_16x16x32_bf16(a[mi], b[ni], acc[mi][ni], 0, 0, 0);
    }
#pragma unroll
    for (int mi = 0; mi < 4; ++mi) {
#pragma unroll
        for (int r = 0; r < 4; ++r) {
            int row = m0 + mi * 16 + lh * 4 + r;
            float sc = (MODE == 0 && row < M) ? scale[row] : 1.0f;
            float p = 0.0f;
#pragma unroll
            for (int ni = 0; ni < 4; ++ni) {
                int col = n0 + ni * 16 + ll;
                float v = acc[mi][ni][r] + bias[col];
                if (MODE == 0) v = fmaxf(v, 0.0f) * sc;
                else p += v * v;
                if (row < M) Cout[(size_t)row * DIM + col] = f2bf(v);
            }
            if (MODE == 1) {
#pragma unroll
                for (int m = 1; m < 16; m <<= 1) p += __shfl_xor(p, m);
                if (ll == 0) rowsq[wave][mi * 16 + lh * 4 + r] = p;
            }
        }
    }
    if (MODE == 1) {
        __syncthreads();
        if (threadIdx.x < 64) {
            int lr = threadIdx.x;
            float s = rowsq[0][lr] + rowsq[1][lr] + rowsq[2][lr] + rowsq[3][lr];
            float l = (m0 + lr < M) ? sqrtf(s) : 0.0f;
#pragma unroll
            for (int m = 32; m > 0; m >>= 1) l += __shfl_down(l, m);
            if (lr == 0) atomicAdd(norm_sum, l);
        }
    }
}

// One block per graph (n2g is sorted): binary-search node range, no atomics,
// factor computed inline. Writes every output element exactly once.
__global__ __launch_bounds__(256) void pool_kernel(const ushort* __restrict__ h2,
                                                   const int* __restrict__ n2g,
                                                   const float* __restrict__ norm_sum,
                                                   float* __restrict__ out) {
    int g = blockIdx.x, f = threadIdx.x;
    int lo = 0, hi = NODES;
    while (lo < hi) { int mid = (lo + hi) >> 1; if (n2g[mid] < g) lo = mid + 1; else hi = mid; }
    int start = lo;
    hi = NODES;
    while (lo < hi) { int mid = (lo + hi) >> 1; if (n2g[mid] < g + 1) lo = mid + 1; else hi = mid; }
    int end = lo;
    float acc = 0.0f;
    int i = start;
    for (; i + 3 < end; i += 4) {
        acc += (bf2f((uint)h2[(size_t)(i + 0) * DIM + f]) + bf2f((uint)h2[(size_t)(i + 1) * DIM + f]))
             + (bf2f((uint)h2[(size_t)(i + 2) * DIM + f]) + bf2f((uint)h2[(size_t)(i + 3) * DIM + f]));
    }
    for (; i < end; ++i) acc += bf2f((uint)h2[(size_t)i * DIM + f]);
    float factor = 16.0f * (float)NODES / *norm_sum;   // sqrt(256) / mean row norm
    out[(size_t)g * DIM + f] = acc * factor;
}

extern "C" void kernel_launch(void* const* d_in, const int* in_sizes, int n_in,
                              void* d_out, int out_size, void* d_ws, size_t ws_size,
                              hipStream_t stream) {
    const float* x  = (const float*)d_in[0];
    const float* W1 = (const float*)d_in[1];
    const float* b1 = (const float*)d_in[2];
    const float* W2 = (const float*)d_in[3];
    const float* b2 = (const float*)d_in[4];
    const int* src = (const int*)d_in[5];
    const int* dst = (const int*)d_in[6];
    const int* n2g = (const int*)d_in[7];
    float* out = (float*)d_out;

    char* ws = (char*)d_ws;
    size_t off = 0;
    auto alloc = [&](size_t bytes) {
        char* p = ws + off;
        off = (off + bytes + 255) & ~(size_t)255;
        return p;
    };
    uint* histIn    = (uint*)alloc((size_t)HBLOCKS * 2 * HALF_W * 4);  // 25.6 MB
    uint* histOut   = (uint*)alloc((size_t)HBLOCKS * 2 * HALF_W * 4);  // 25.6 MB
    int* deg_in     = (int*)alloc(NODES * 4);
    float* out_norm = (float*)alloc(NODES * 4);
    float* in_norm  = (float*)alloc(NODES * 4);
    int* row_start  = (int*)alloc((NODES + 1) * 4);
    int* src_sorted = (int*)alloc(EDGES * 4);
    int* block_sums = (int*)alloc(RB * 4);
    float* norm_sum = (float*)alloc(4);
    ushort* W1T     = (ushort*)alloc((size_t)DIM * FIN * 2);   // [256][128]
    ushort* W2T     = (ushort*)alloc((size_t)DIM * DIM * 2);   // [256][256]
    // Aliased feature regions:
    // P0: xs [PAD_M][128] bf16 -> low half of A2 | P1: A1 [PAD_M][128] -> high half of A2
    // H : h1s [PAD_M][256] bf16 -> reused as h2 (agg2 consumed h1s before gemm2 writes)
    ushort* xs  = (ushort*)alloc((size_t)PAD_M * FIN * 2);
    ushort* A1  = (ushort*)alloc((size_t)PAD_M * FIN * 2);
    ushort* h1s = (ushort*)alloc((size_t)PAD_M * DIM * 2);
    ushort* A2 = xs;          // [PAD_M][256] bf16, overlays P0+P1
    ushort* h2 = h1s;         // [PAD_M][256] bf16, overlays H

    // CSR build + prep: 5 dispatches, zero global atomics.
    hist2_kernel<<<2 * HBLOCKS, 256, 0, stream>>>(src, dst, histIn, histOut);
    reduce_hist_kernel<<<RB, 256, 0, stream>>>(histIn, histOut, deg_in, in_norm, out_norm, block_sums);
    scan_blocksums<<<1, 256, 0, stream>>>(block_sums, row_start, norm_sum, RB, NODES);
    scanfinal_prep_kernel<<<RB + PRESCALE_BLOCKS + FIN * DIM / 256 + DIM * DIM / 256, 256, 0, stream>>>(
        deg_in, block_sums, row_start, x, out_norm, xs, W1, W1T, W2, W2T);
    scatter_lds_kernel<<<HBLOCKS, 256, 0, stream>>>(src, dst, histIn, row_start, src_sorted);

    // Layer 1
    agg_kernel<FIN><<<(NODES + 3) / 4, 256, 0, stream>>>(xs, row_start, src_sorted, in_norm, A1);
    gemm_mfma_kernel<FIN, 0><<<PAD_M / 64, 256, 0, stream>>>(A1, W1T, b1, h1s, out_norm, norm_sum, NODES);

    // Layer 2 (gemm2 fuses row-norm accumulation, writes bf16 h2)
    agg_kernel<DIM><<<(NODES + 3) / 4, 256, 0, stream>>>(h1s, row_start, src_sorted, in_norm, A2);
    gemm_mfma_kernel<DIM, 1><<<PAD_M / 64, 256, 0, stream>>>(A2, W2T, b2, h2, nullptr, norm_sum, NODES);

    // Per-graph sum-pool with inline factor; covers all graphs, no memset needed.
    pool_kernel<<<GRAPHS, 256, 0, stream>>>(h2, n2g, norm_sum, out);
}